// Round 1
// baseline (1205.860 us; speedup 1.0000x reference)
//
#include <hip/hip_runtime.h>
#include <hip/hip_bf16.h>
#include <math.h>

#define B_ 128
#define S_ 512
#define EMB_ 200
#define HID_ 128
#define NT_ 20
#define G4_ 512   // 4*HID

__device__ __forceinline__ float sigm_(float x) {
    x = fminf(fmaxf(x, -30.f), 30.f);
    float e = __expf(-x);
    return 1.f / (1.f + e);
}
__device__ __forceinline__ float tanh_(float x) {
    x = fminf(fmaxf(x, -15.f), 15.f);
    float e = __expf(2.f * x);
    return (e - 1.f) / (e + 1.f);
}

// ---------- detect mask dtype (bool bytes vs int32) ----------
__global__ void k_detect(const unsigned char* mask, int* flag) {
    __shared__ int partial[4];
    int tid = threadIdx.x;
    int s = 0;
    // first B_*S_ bytes are safe to read under either interpretation
    for (int i = tid; i < B_ * S_; i += 256) {
        if (i & 3) s += mask[i];
    }
    for (int m = 32; m >= 1; m >>= 1) s += __shfl_xor(s, m);
    if ((tid & 63) == 0) partial[tid >> 6] = s;
    __syncthreads();
    if (tid == 0) {
        int tot = partial[0] + partial[1] + partial[2] + partial[3];
        flag[0] = (tot > 0) ? 1 : 0;  // 1 => 1-byte bool layout, 0 => int32
    }
}

// ---------- K1: xg[m][g] = dot(embedding[sentence[m]], W_ih[g]) + b_ih[g] + b_hh[g] ----------
__global__ __launch_bounds__(512, 2) void k_xg(const int* __restrict__ sentence,
                                               const float* __restrict__ embedding,
                                               const float* __restrict__ W_ih,
                                               const float* __restrict__ b_ih,
                                               const float* __restrict__ b_hh,
                                               __hip_bfloat16* __restrict__ xg) {
    __shared__ __align__(16) float emb[32 * EMB_];
    __shared__ int ids[32];
    int tid = threadIdx.x;
    int m0 = blockIdx.x * 32;
    if (tid < 32) ids[tid] = sentence[m0 + tid];
    __syncthreads();
    for (int idx = tid; idx < 32 * EMB_; idx += 512) {
        int r = idx / EMB_;
        int e = idx - r * EMB_;
        emb[idx] = embedding[(size_t)ids[r] * EMB_ + e];
    }
    __syncthreads();
    int g = tid;
    float acc[32];
#pragma unroll
    for (int r = 0; r < 32; r++) acc[r] = 0.f;
    const float4* wp = (const float4*)(W_ih + (size_t)g * EMB_);
    for (int e4 = 0; e4 < EMB_ / 4; e4++) {
        float4 w4 = wp[e4];
#pragma unroll
        for (int r = 0; r < 32; r++) {
            float4 h4 = *(const float4*)(emb + r * EMB_ + e4 * 4);
            acc[r] += w4.x * h4.x + w4.y * h4.y + w4.z * h4.z + w4.w * h4.w;
        }
    }
    float bias = b_ih[g] + b_hh[g];
#pragma unroll
    for (int r = 0; r < 32; r++) {
        xg[(size_t)(m0 + r) * G4_ + g] = __float2bfloat16(acc[r] + bias);
    }
}

// ---------- K2: per-batch LSTM scan + emissions ----------
__global__ __launch_bounds__(512, 2) void k_lstm(const __hip_bfloat16* __restrict__ xg,
                                                 const float* __restrict__ W_hh,
                                                 const float* __restrict__ W_dec,
                                                 const float* __restrict__ b_dec,
                                                 float* __restrict__ em_out) {
    __shared__ __align__(16) float h_lds[HID_];
    __shared__ __align__(16) float gate_lds[G4_];
    __shared__ __align__(16) float wdec[NT_ * HID_];
    __shared__ float bdec[NT_];
    int b = blockIdx.x;
    int tid = threadIdx.x;

    // W_hh row for this gate into registers (128 floats)
    float4 w[32];
    const float4* wrow = (const float4*)(W_hh + (size_t)tid * HID_);
#pragma unroll
    for (int k = 0; k < 32; k++) w[k] = wrow[k];

    for (int idx = tid; idx < NT_ * HID_; idx += 512) wdec[idx] = W_dec[idx];
    if (tid < NT_) bdec[tid] = b_dec[tid];
    if (tid < HID_) h_lds[tid] = 0.f;
    float c = 0.f;
    int gtype = tid >> 7;  // 0:i 1:f 2:g 3:o (wave-uniform)
    __syncthreads();

    const __hip_bfloat16* xgb = xg + (size_t)b * S_ * G4_;
    float* emb_ = em_out + (size_t)b * S_ * NT_;

    for (int t = 0; t < S_; t++) {
        float xgv = __bfloat162float(xgb[(size_t)t * G4_ + tid]);
        float a0 = 0.f, a1 = 0.f, a2 = 0.f, a3 = 0.f;
#pragma unroll
        for (int k = 0; k < 32; k++) {
            float4 h4 = ((const float4*)h_lds)[k];
            a0 += w[k].x * h4.x;
            a1 += w[k].y * h4.y;
            a2 += w[k].z * h4.z;
            a3 += w[k].w * h4.w;
        }
        float pre = xgv + ((a0 + a1) + (a2 + a3));
        // activate in the parallel phase (gtype is wave-uniform: no divergence)
        float act = (gtype == 2) ? tanh_(pre) : sigm_(pre);
        gate_lds[tid] = act;
        __syncthreads();
        if (tid < HID_) {
            float i_ = gate_lds[tid];
            float f_ = gate_lds[HID_ + tid];
            float g_ = gate_lds[2 * HID_ + tid];
            float o_ = gate_lds[3 * HID_ + tid];
            c = f_ * c + i_ * g_;
            float h = o_ * tanh_(c);
            h_lds[tid] = h;
        }
        __syncthreads();
        // emissions: 20 tags x 8 lanes, 16 MACs each + shuffle reduce
        if (tid < NT_ * 8) {
            int tag = tid >> 3, l8 = tid & 7;
            const float4* wd4 = (const float4*)(wdec + tag * HID_ + l8 * 16);
            const float4* hh4 = (const float4*)(h_lds + l8 * 16);
            float p = 0.f;
#pragma unroll
            for (int q = 0; q < 4; q++) {
                float4 a = wd4[q], v = hh4[q];
                p += a.x * v.x + a.y * v.y + a.z * v.z + a.w * v.w;
            }
            p += __shfl_xor(p, 1);
            p += __shfl_xor(p, 2);
            p += __shfl_xor(p, 4);
            if (l8 == 0) emb_[(size_t)t * NT_ + tag] = p + bdec[tag];
        }
    }
}

// ---------- K3: per-batch CRF numerator + forward algorithm ----------
__global__ __launch_bounds__(256, 2) void k_crf(const float* __restrict__ em,
                                                const int* __restrict__ tags,
                                                const void* __restrict__ mask,
                                                const int* __restrict__ flag,
                                                const float* __restrict__ start_trans,
                                                const float* __restrict__ end_trans,
                                                const float* __restrict__ trans,
                                                float* __restrict__ nll) {
    __shared__ float em_s[S_ * NT_];     // 40 KB
    __shared__ float trans_s[NT_ * NT_];
    __shared__ float score[2][NT_];
    __shared__ int tags_s[S_];
    __shared__ unsigned char mask_s[S_];
    __shared__ float fin[NT_];
    __shared__ float num_sh;

    int b = blockIdx.x;
    int tid = threadIdx.x;
    const float* emb_ = em + (size_t)b * S_ * NT_;

    for (int i = tid; i < S_ * NT_; i += 256) em_s[i] = emb_[i];
    for (int i = tid; i < NT_ * NT_; i += 256) trans_s[i] = trans[i];
    for (int i = tid; i < S_; i += 256) tags_s[i] = tags[b * S_ + i];
    int fl = flag[0];
    for (int i = tid; i < S_; i += 256) {
        mask_s[i] = fl ? ((const unsigned char*)mask)[b * S_ + i]
                       : (unsigned char)(((const int*)mask)[b * S_ + i] != 0);
    }
    __syncthreads();
    if (tid < NT_) score[0][tid] = start_trans[tid] + em_s[tid];
    float num = 0.f;
    int lastTag = 0;
    if (tid == 192) {
        lastTag = tags_s[0];
        num = start_trans[lastTag] + em_s[lastTag];
    }
    __syncthreads();

    int tag = tid >> 3, l8 = tid & 7;
    int cur = 0;
    for (int t = 1; t < S_; t++) {
        if (tid < NT_ * 8) {
            float v0 = score[cur][l8] + trans_s[l8 * NT_ + tag];
            float v1 = score[cur][l8 + 8] + trans_s[(l8 + 8) * NT_ + tag];
            float v2 = (l8 < 4) ? score[cur][l8 + 16] + trans_s[(l8 + 16) * NT_ + tag]
                                : -INFINITY;
            float m = fmaxf(fmaxf(v0, v1), v2);
            m = fmaxf(m, __shfl_xor(m, 4));
            m = fmaxf(m, __shfl_xor(m, 2));
            m = fmaxf(m, __shfl_xor(m, 1));
            float s = __expf(v0 - m) + __expf(v1 - m) + ((l8 < 4) ? __expf(v2 - m) : 0.f);
            s += __shfl_xor(s, 4);
            s += __shfl_xor(s, 2);
            s += __shfl_xor(s, 1);
            if (l8 == 0) {
                float nxt = m + __logf(s) + em_s[t * NT_ + tag];
                score[cur ^ 1][tag] = mask_s[t] ? nxt : score[cur][tag];
            }
        }
        if (tid == 192) {
            if (mask_s[t]) {
                int tg = tags_s[t];
                num += trans_s[lastTag * NT_ + tg] + em_s[t * NT_ + tg];
                lastTag = tg;
            }
        }
        __syncthreads();
        cur ^= 1;
    }
    if (tid == 192) num_sh = num + end_trans[lastTag];
    if (tid < NT_) fin[tid] = score[cur][tid] + end_trans[tid];
    __syncthreads();
    if (tid == 0) {
        float m = fin[0];
#pragma unroll
        for (int i = 1; i < NT_; i++) m = fmaxf(m, fin[i]);
        float s = 0.f;
#pragma unroll
        for (int i = 0; i < NT_; i++) s += __expf(fin[i] - m);
        float den = m + __logf(s);
        nll[b] = den - num_sh;
    }
}

// ---------- K4: mean over batch ----------
__global__ void k_final(const float* __restrict__ nll, float* __restrict__ out) {
    __shared__ float sums[2];
    int tid = threadIdx.x;  // 128 threads
    float v = nll[tid];
    for (int m = 32; m >= 1; m >>= 1) v += __shfl_xor(v, m);
    if ((tid & 63) == 0) sums[tid >> 6] = v;
    __syncthreads();
    if (tid == 0) out[0] = (sums[0] + sums[1]) * (1.f / (float)B_);
}

extern "C" void kernel_launch(void* const* d_in, const int* in_sizes, int n_in,
                              void* d_out, int out_size, void* d_ws, size_t ws_size,
                              hipStream_t stream) {
    const int* sentence = (const int*)d_in[0];
    const int* tags = (const int*)d_in[1];
    const void* mask = d_in[2];
    const float* embedding = (const float*)d_in[3];
    const float* W_ih = (const float*)d_in[4];
    const float* W_hh = (const float*)d_in[5];
    const float* b_ih = (const float*)d_in[6];
    const float* b_hh = (const float*)d_in[7];
    const float* W_dec = (const float*)d_in[8];
    const float* b_dec = (const float*)d_in[9];
    const float* start_trans = (const float*)d_in[10];
    const float* end_trans = (const float*)d_in[11];
    const float* trans = (const float*)d_in[12];

    char* ws = (char*)d_ws;
    int* flag = (int*)ws;                                   // 4 B (pad to 256)
    __hip_bfloat16* xg = (__hip_bfloat16*)(ws + 256);       // B*S*512 bf16 = 64 MiB
    size_t xg_bytes = (size_t)B_ * S_ * G4_ * 2;
    float* em = (float*)(ws + 256 + xg_bytes);              // B*S*20 f32 = 5 MiB
    size_t em_bytes = (size_t)B_ * S_ * NT_ * 4;
    float* nllp = (float*)(ws + 256 + xg_bytes + em_bytes); // 128 f32

    k_detect<<<1, 256, 0, stream>>>((const unsigned char*)mask, flag);
    k_xg<<<(B_ * S_) / 32, 512, 0, stream>>>(sentence, embedding, W_ih, b_ih, b_hh, xg);
    k_lstm<<<B_, 512, 0, stream>>>(xg, W_hh, W_dec, b_dec, em);
    k_crf<<<B_, 256, 0, stream>>>(em, tags, mask, flag, start_trans, end_trans, trans, nllp);
    k_final<<<1, 128, 0, stream>>>(nllp, (float*)d_out);
}